// Round 1
// baseline (2151.018 us; speedup 1.0000x reference)
//
#include <hip/hip_runtime.h>
#include <stdint.h>

typedef unsigned short u16;
typedef __attribute__((ext_vector_type(8))) short short8;
typedef __attribute__((ext_vector_type(4))) float f32x4;

#define DEV __device__ __forceinline__

DEV u16 f2bf(float f) {
  union { float f; uint32_t u; } c; c.f = f;
  uint32_t u = c.u;
  uint32_t r = u + 0x7fffu + ((u >> 16) & 1u);  // RNE
  return (u16)(r >> 16);
}

DEV void g2l16(const void* g, void* l) {
  __builtin_amdgcn_global_load_lds((__attribute__((address_space(1))) void*)(g),
                                   (__attribute__((address_space(3))) void*)(l),
                                   16, 0, 0);
}

// ---------------- positional embedding (PositionEmbeddingSine) ----------------
__global__ void pos_kernel(float* __restrict__ pos) {
  int n = blockIdx.x;
  float yv = (float)((n >> 5) + 1) / (32.0f + 1e-6f) * 6.283185307179586f;
  float xv = (float)((n & 31) + 1) / (32.0f + 1e-6f) * 6.283185307179586f;
#pragma unroll
  for (int i = 0; i < 3; i++) {
    int d = threadIdx.x + i * 256;
    int dd = (d < 384) ? d : d - 384;
    float base = (d < 384) ? yv : xv;
    float ex = (float)(dd & ~1) / 384.0f;     // 2*floor(dd/2)/384
    float arg = base / powf(10000.0f, ex);
    pos[(size_t)n * 768 + d] = (dd & 1) ? cosf(arg) : sinf(arg);
  }
}

// ---------------- conv_w fp32 [768][256] -> bf16 (already N x K) ----------------
__global__ void convw_kernel(const float* __restrict__ src, u16* __restrict__ dst) {
  int i = blockIdx.x * 256 + threadIdx.x;
  dst[i] = f2bf(src[i]);
}

// ---------------- 32x32 tile transpose fp32 -> bf16 ----------------
DEV void tile_tr32(const float* __restrict__ src, u16* __restrict__ dst,
                   int R, int C, int tr, int tc, float (*tile)[33]) {
  int tx = threadIdx.x & 31, ty = threadIdx.x >> 5;  // 32 x 8
#pragma unroll
  for (int i = 0; i < 32; i += 8)
    tile[ty + i][tx] = src[(size_t)(tr * 32 + ty + i) * C + tc * 32 + tx];
  __syncthreads();
#pragma unroll
  for (int i = 0; i < 32; i += 8)
    dst[(size_t)(tc * 32 + ty + i) * R + tr * 32 + tx] = f2bf(tile[tx][ty + i]);
}

// all four weights of one layer, transposed to [N][K] bf16, one launch
__global__ void wconv_kernel(const float* __restrict__ qkv_w, const float* __restrict__ out_w,
                             const float* __restrict__ m1w, const float* __restrict__ m2w,
                             u16* __restrict__ wqkv, u16* __restrict__ wout,
                             u16* __restrict__ wm1, u16* __restrict__ wm2, int layer) {
  __shared__ float tile[32][33];
  int tid = blockIdx.x;
  if (tid < 1728) {                                   // qkv_w: [768][2304] -> [2304][768]
    tile_tr32(qkv_w + (size_t)layer * 768 * 2304, wqkv, 768, 2304, tid / 72, tid % 72, tile);
  } else if (tid < 2304) {                            // out_w: [768][768]
    int t2 = tid - 1728;
    tile_tr32(out_w + (size_t)layer * 768 * 768, wout, 768, 768, t2 / 24, t2 % 24, tile);
  } else if (tid < 4608) {                            // mlp_w1: [768][3072] -> [3072][768]
    int t3 = tid - 2304;
    tile_tr32(m1w + (size_t)layer * 768 * 3072, wm1, 768, 3072, t3 / 96, t3 % 96, tile);
  } else {                                            // mlp_w2: [3072][768] -> [768][3072]
    int t4 = tid - 4608;
    tile_tr32(m2w + (size_t)layer * 3072 * 768, wm2, 3072, 768, t4 / 24, t4 % 24, tile);
  }
}

// c_f [B][256][1024] fp32 -> aconv [B][1024][256] bf16
__global__ void cf_tr_kernel(const float* __restrict__ c_f, u16* __restrict__ aconv) {
  __shared__ float tile[32][33];
  int b = blockIdx.z;
  tile_tr32(c_f + (size_t)b * 256 * 1024, aconv + (size_t)b * 1024 * 256,
            256, 1024, blockIdx.y, blockIdx.x, tile);
}

// x [B][1024][768] fp32 -> out [B][768][1024] fp32
__global__ void out_tr_kernel(const float* __restrict__ x, float* __restrict__ out) {
  __shared__ float tile[32][33];
  int b = blockIdx.z;
  const float* src = x + (size_t)b * 1024 * 768;
  float* dst = out + (size_t)b * 768 * 1024;
  int tr = blockIdx.y, tc = blockIdx.x;  // tr over n (32 tiles), tc over d (24 tiles)
  int tx = threadIdx.x & 31, ty = threadIdx.x >> 5;
#pragma unroll
  for (int i = 0; i < 32; i += 8)
    tile[ty + i][tx] = src[(size_t)(tr * 32 + ty + i) * 768 + tc * 32 + tx];
  __syncthreads();
#pragma unroll
  for (int i = 0; i < 32; i += 8)
    dst[(size_t)(tc * 32 + ty + i) * 1024 + tr * 32 + tx] = tile[tx][ty + i];
}

// ---------------- LayerNorm: fp32 in -> bf16 out ----------------
__global__ __launch_bounds__(256) void ln_kernel(const float* __restrict__ x,
                                                 const float* __restrict__ w,
                                                 const float* __restrict__ bsh,
                                                 u16* __restrict__ y) {
  int row = blockIdx.x, t = threadIdx.x;
  const float* xr = x + (size_t)row * 768;
  float v[3], s = 0.f, sq = 0.f;
#pragma unroll
  for (int i = 0; i < 3; i++) { v[i] = xr[t + i * 256]; s += v[i]; sq += v[i] * v[i]; }
#pragma unroll
  for (int off = 32; off; off >>= 1) { s += __shfl_xor(s, off); sq += __shfl_xor(sq, off); }
  __shared__ float ss[4], ssq[4];
  if ((t & 63) == 0) { ss[t >> 6] = s; ssq[t >> 6] = sq; }
  __syncthreads();
  s = ss[0] + ss[1] + ss[2] + ss[3];
  sq = ssq[0] + ssq[1] + ssq[2] + ssq[3];
  float mean = s * (1.0f / 768.0f);
  float var = sq * (1.0f / 768.0f) - mean * mean;
  float rs = rsqrtf(var + 1e-5f);
#pragma unroll
  for (int i = 0; i < 3; i++) {
    int c = t + i * 256;
    y[(size_t)row * 768 + c] = f2bf((v[i] - mean) * rs * w[c] + bsh[c]);
  }
}

// ---------------- GEMM: C[M,N] = A[M,K](bf16) @ BT[N,K](bf16)^T, epilogues ----------------
constexpr int EPI_BF16 = 0, EPI_BIAS_RES = 1, EPI_BIAS_GELU = 2, EPI_BIAS_POS = 3;

template <int EPI>
__global__ __launch_bounds__(256, 2) void gemm_bt(
    const u16* __restrict__ A, const u16* __restrict__ BT,
    const float* __restrict__ bias, const float* __restrict__ res,
    void* __restrict__ Cout, int M, int N, int K) {
  __shared__ __align__(16) u16 As[128 * 32];
  __shared__ __align__(16) u16 Bs[128 * 32];
  const int t = threadIdx.x;
  const int w = t >> 6, l = t & 63, lr = l & 15, quad = l >> 4;
  const int bm = blockIdx.y * 128, bn = blockIdx.x * 128;
  const int wm = (w & 1) * 64, wn = (w >> 1) * 64;
  f32x4 acc[4][4];
#pragma unroll
  for (int i = 0; i < 4; i++)
#pragma unroll
    for (int j = 0; j < 4; j++) acc[i][j] = (f32x4){0.f, 0.f, 0.f, 0.f};
  const int c0 = t, c1 = 256 + t;
  const size_t a0 = (size_t)(bm + (c0 >> 2)) * K + (c0 & 3) * 8;
  const size_t a1 = (size_t)(bm + (c1 >> 2)) * K + (c1 & 3) * 8;
  const size_t b0 = (size_t)(bn + (c0 >> 2)) * K + (c0 & 3) * 8;
  const size_t b1 = (size_t)(bn + (c1 >> 2)) * K + (c1 & 3) * 8;
  for (int k0 = 0; k0 < K; k0 += 32) {
    g2l16(A + a0 + k0, As + c0 * 8);
    g2l16(A + a1 + k0, As + c1 * 8);
    g2l16(BT + b0 + k0, Bs + c0 * 8);
    g2l16(BT + b1 + k0, Bs + c1 * 8);
    __syncthreads();
    short8 af[4], bf[4];
#pragma unroll
    for (int mi = 0; mi < 4; mi++) af[mi] = *(const short8*)(As + (wm + mi * 16 + lr) * 32 + quad * 8);
#pragma unroll
    for (int nj = 0; nj < 4; nj++) bf[nj] = *(const short8*)(Bs + (wn + nj * 16 + lr) * 32 + quad * 8);
#pragma unroll
    for (int mi = 0; mi < 4; mi++)
#pragma unroll
      for (int nj = 0; nj < 4; nj++)
        acc[mi][nj] = __builtin_amdgcn_mfma_f32_16x16x32_bf16(af[mi], bf[nj], acc[mi][nj], 0, 0, 0);
    __syncthreads();
  }
#pragma unroll
  for (int mi = 0; mi < 4; mi++) {
    const int rowb = bm + wm + mi * 16 + quad * 4;
#pragma unroll
    for (int nj = 0; nj < 4; nj++) {
      const int gn = bn + wn + nj * 16 + lr;
#pragma unroll
      for (int r = 0; r < 4; r++) {
        const size_t idx = (size_t)(rowb + r) * N + gn;
        float v = acc[mi][nj][r];
        if constexpr (EPI == EPI_BF16) {
          ((u16*)Cout)[idx] = f2bf(v);
        } else if constexpr (EPI == EPI_BIAS_RES) {
          ((float*)Cout)[idx] = v + bias[gn] + res[idx];
        } else if constexpr (EPI == EPI_BIAS_GELU) {
          float xg = v + bias[gn];
          ((u16*)Cout)[idx] = f2bf(0.5f * xg * (1.0f + erff(xg * 0.70710678118f)));
        } else {  // EPI_BIAS_POS (conv epilogue, N==768)
          ((float*)Cout)[idx] = v + bias[gn] + res[(size_t)((rowb + r) & 1023) * N + gn];
        }
      }
    }
  }
}

// ---------------- flash attention: qkv bf16 [4096][2304] -> o bf16 [4096][768] ----------------
__global__ __launch_bounds__(256, 2) void attn_kernel(const u16* __restrict__ qkv,
                                                      u16* __restrict__ o) {
  __shared__ __align__(16) u16 Ks[64 * 64];      // K block [key][d]
  __shared__ __align__(16) u16 Vs[64 * 72];      // V^T block [d][key], padded
  __shared__ __align__(16) u16 Ps[4][32 * 72];   // per-wave P, padded
  const int t = threadIdx.x;
  const int w = t >> 6, l = t & 63, lr = l & 15, quad = l >> 4;
  const int bh = blockIdx.y, b = bh / 12, h = bh % 12;
  const int qbase = blockIdx.x * 128 + w * 32;

  short8 aq[2][2];
#pragma unroll
  for (int mi = 0; mi < 2; mi++)
#pragma unroll
    for (int ks = 0; ks < 2; ks++)
      aq[mi][ks] = *(const short8*)(qkv + (size_t)(b * 1024 + qbase + mi * 16 + lr) * 2304 +
                                    h * 64 + ks * 32 + quad * 8);
  float m_st[2][4], l_st[2][4];
  f32x4 accO[2][4];
#pragma unroll
  for (int mi = 0; mi < 2; mi++) {
#pragma unroll
    for (int r = 0; r < 4; r++) { m_st[mi][r] = -1e30f; l_st[mi][r] = 0.f; }
#pragma unroll
    for (int dj = 0; dj < 4; dj++) accO[mi][dj] = (f32x4){0.f, 0.f, 0.f, 0.f};
  }

  for (int jb = 0; jb < 16; jb++) {
    const int kb = jb * 64;
    // stage K [64][64] via async 16B
#pragma unroll
    for (int i = 0; i < 2; i++) {
      int c = i * 256 + t;
      g2l16(qkv + (size_t)(b * 1024 + kb + (c >> 3)) * 2304 + 768 + h * 64 + (c & 7) * 8,
            Ks + c * 8);
    }
    // stage V^T [d][key] (coalesced global reads, scalar LDS writes)
    {
      int d = t & 63, kg = t >> 6;
      const u16* vp = qkv + (size_t)(b * 1024 + kb + kg * 16) * 2304 + 1536 + h * 64 + d;
#pragma unroll
      for (int kk = 0; kk < 16; kk++) Vs[d * 72 + kg * 16 + kk] = vp[(size_t)kk * 2304];
    }
    __syncthreads();
    // S = Q @ K^T
    f32x4 s[2][4];
#pragma unroll
    for (int mi = 0; mi < 2; mi++)
#pragma unroll
      for (int nj = 0; nj < 4; nj++) s[mi][nj] = (f32x4){0.f, 0.f, 0.f, 0.f};
#pragma unroll
    for (int ks = 0; ks < 2; ks++) {
      short8 bk[4];
#pragma unroll
      for (int nj = 0; nj < 4; nj++)
        bk[nj] = *(const short8*)(Ks + (nj * 16 + lr) * 64 + ks * 32 + quad * 8);
#pragma unroll
      for (int mi = 0; mi < 2; mi++)
#pragma unroll
        for (int nj = 0; nj < 4; nj++)
          s[mi][nj] = __builtin_amdgcn_mfma_f32_16x16x32_bf16(aq[mi][ks], bk[nj], s[mi][nj], 0, 0, 0);
    }
    // online softmax (rows = mi*16 + quad*4 + r; cols across 16 lanes x 4 tiles)
    u16* Pw = Ps[w];
#pragma unroll
    for (int mi = 0; mi < 2; mi++)
#pragma unroll
      for (int r = 0; r < 4; r++) {
        float v[4], mx = -1e30f;
#pragma unroll
        for (int nj = 0; nj < 4; nj++) { v[nj] = s[mi][nj][r] * 0.125f; mx = fmaxf(mx, v[nj]); }
#pragma unroll
        for (int off = 1; off < 16; off <<= 1) mx = fmaxf(mx, __shfl_xor(mx, off));
        float mold = m_st[mi][r];
        float mnew = fmaxf(mold, mx);
        float alpha = __expf(mold - mnew);
        float rs = 0.f;
#pragma unroll
        for (int nj = 0; nj < 4; nj++) { v[nj] = __expf(v[nj] - mnew); rs += v[nj]; }
#pragma unroll
        for (int off = 1; off < 16; off <<= 1) rs += __shfl_xor(rs, off);
        m_st[mi][r] = mnew;
        l_st[mi][r] = l_st[mi][r] * alpha + rs;
#pragma unroll
        for (int dj = 0; dj < 4; dj++) accO[mi][dj][r] *= alpha;
        int rowl = (mi * 16 + quad * 4 + r) * 72;
#pragma unroll
        for (int nj = 0; nj < 4; nj++) Pw[rowl + nj * 16 + lr] = f2bf(v[nj]);
      }
    // O += P @ V (wave-local LDS dependency; compiler inserts lgkmcnt waits)
#pragma unroll
    for (int ks = 0; ks < 2; ks++) {
      short8 ap[2], bv[4];
#pragma unroll
      for (int mi = 0; mi < 2; mi++)
        ap[mi] = *(const short8*)(Pw + (mi * 16 + lr) * 72 + ks * 32 + quad * 8);
#pragma unroll
      for (int dj = 0; dj < 4; dj++)
        bv[dj] = *(const short8*)(Vs + (dj * 16 + lr) * 72 + ks * 32 + quad * 8);
#pragma unroll
      for (int mi = 0; mi < 2; mi++)
#pragma unroll
        for (int dj = 0; dj < 4; dj++)
          accO[mi][dj] = __builtin_amdgcn_mfma_f32_16x16x32_bf16(ap[mi], bv[dj], accO[mi][dj], 0, 0, 0);
    }
    __syncthreads();
  }
  // epilogue: O /= l, write bf16 [token][h*64+d]
#pragma unroll
  for (int mi = 0; mi < 2; mi++)
#pragma unroll
    for (int r = 0; r < 4; r++) {
      float inv = 1.0f / l_st[mi][r];
      size_t grow = (size_t)(b * 1024 + qbase + mi * 16 + quad * 4 + r);
#pragma unroll
      for (int dj = 0; dj < 4; dj++)
        o[grow * 768 + h * 64 + dj * 16 + lr] = f2bf(accO[mi][dj][r] * inv);
    }
}

// ---------------- driver ----------------
extern "C" void kernel_launch(void* const* d_in, const int* in_sizes, int n_in,
                              void* d_out, int out_size, void* d_ws, size_t ws_size,
                              hipStream_t stream) {
  (void)in_sizes; (void)n_in; (void)out_size; (void)ws_size;
  const float* c_f    = (const float*)d_in[0];
  const float* conv_w = (const float*)d_in[1];
  const float* conv_b = (const float*)d_in[2];
  const float* ln1_w  = (const float*)d_in[3];
  const float* ln1_b  = (const float*)d_in[4];
  const float* qkv_w  = (const float*)d_in[5];
  const float* out_w  = (const float*)d_in[6];
  const float* out_b  = (const float*)d_in[7];
  const float* ln2_w  = (const float*)d_in[8];
  const float* ln2_b  = (const float*)d_in[9];
  const float* m1w    = (const float*)d_in[10];
  const float* m1b    = (const float*)d_in[11];
  const float* m2w    = (const float*)d_in[12];
  const float* m2b    = (const float*)d_in[13];
  float* out = (float*)d_out;

  char* p = (char*)d_ws;
  auto alloc = [&](size_t bytes) { char* q = p; p += (bytes + 255) & ~(size_t)255; return q; };
  float* pos  = (float*)alloc(1024ull * 768 * 4);
  float* x    = (float*)alloc(4096ull * 768 * 4);
  u16* y      = (u16*)alloc(4096ull * 768 * 2);
  u16* qkvb   = (u16*)alloc(4096ull * 2304 * 2);
  u16* ob     = (u16*)alloc(4096ull * 768 * 2);
  u16* hb     = (u16*)alloc(4096ull * 3072 * 2);
  u16* aconv  = (u16*)alloc(4096ull * 256 * 2);
  u16* convw  = (u16*)alloc(768ull * 256 * 2);
  u16* wqkv   = (u16*)alloc(2304ull * 768 * 2);
  u16* wout   = (u16*)alloc(768ull * 768 * 2);
  u16* wm1    = (u16*)alloc(3072ull * 768 * 2);
  u16* wm2    = (u16*)alloc(768ull * 3072 * 2);

  pos_kernel<<<1024, 256, 0, stream>>>(pos);
  convw_kernel<<<768, 256, 0, stream>>>(conv_w, convw);
  cf_tr_kernel<<<dim3(32, 8, 4), 256, 0, stream>>>(c_f, aconv);
  gemm_bt<EPI_BIAS_POS><<<dim3(6, 32), 256, 0, stream>>>(aconv, convw, conv_b, pos, x, 4096, 768, 256);

  for (int lyr = 0; lyr < 8; lyr++) {
    wconv_kernel<<<6912, 256, 0, stream>>>(qkv_w, out_w, m1w, m2w, wqkv, wout, wm1, wm2, lyr);
    ln_kernel<<<4096, 256, 0, stream>>>(x, ln1_w + lyr * 768, ln1_b + lyr * 768, y);
    gemm_bt<EPI_BF16><<<dim3(18, 32), 256, 0, stream>>>(y, wqkv, nullptr, nullptr, qkvb, 4096, 2304, 768);
    attn_kernel<<<dim3(8, 48), 256, 0, stream>>>(qkvb, ob);
    gemm_bt<EPI_BIAS_RES><<<dim3(6, 32), 256, 0, stream>>>(ob, wout, out_b + lyr * 768, x, x, 4096, 768, 768);
    ln_kernel<<<4096, 256, 0, stream>>>(x, ln2_w + lyr * 768, ln2_b + lyr * 768, y);
    gemm_bt<EPI_BIAS_GELU><<<dim3(24, 32), 256, 0, stream>>>(y, wm1, m1b + lyr * 3072, nullptr, hb, 4096, 3072, 768);
    gemm_bt<EPI_BIAS_RES><<<dim3(6, 32), 256, 0, stream>>>(hb, wm2, m2b + lyr * 768, x, x, 4096, 768, 3072);
  }
  out_tr_kernel<<<dim3(24, 32, 4), 256, 0, stream>>>(x, out);
}